// Round 6
// baseline (341.002 us; speedup 1.0000x reference)
//
#include <hip/hip_runtime.h>

// Problem constants (fixed by the reference)
#define B_   2
#define DZ   41
#define HY   400
#define WX   352
#define NVOX 40000               // 40000 = 2500 * 16 exactly
#define PD   43      // DZ+2
#define PH   402     // HY+2
#define PW   354     // WX+2
#define DO_  21
#define HO_  200
#define WO_  176
#define C1   128
#define OPP  (DO_*HO_*WO_)              // 739,200 positions per batch
#define OUT_POS (B_*OPP)                // 1,478,400 (= 46200 * 32 exactly)
#define GRID_CELLS (B_*PD*PH*PW)        // 12,238,488 cells (uint16)
#define GRID_F4  (GRID_CELLS*2/16)      // 1,529,811 exact
#define OMASK_F4 (OUT_POS/16)           // 92,400 exact

// Established: all float tensors f32 in/out; coors int32. R4->R5 lesson: the
// 739200KB/111us fillBuffer dispatches are the HARNESS's d_out/d_ws 0xAA
// re-poison (they persisted with zero memsets in our code) - not ours, maybe
// not even in dur_us. R6: drop zero-out/scatter/relu; omask + dense gather
// k_out writes output once; subm kernels build nbr lists in-block.

// ---- valid downsample taps for one axis, from PADDED input coord ----
// o = pcoord - doff (doff 0..2) valid iff o even and 0 <= o/2 < outdim.
__device__ __forceinline__ int axis_taps(int pcoord, int outdim, int* ds, int* ps) {
    if (pcoord & 1) { ds[0] = 1; ps[0] = pcoord >> 1; return 1; }
    int h = pcoord >> 1, nu = 0;
    if (h < outdim) { ds[nu] = 0; ps[nu] = h; nu++; }
    ds[nu] = 2; ps[nu] = h - 1; nu++;
    return nu;
}

// ---- zero grid (24.5 MB) + omask (1.5 MB) ----
__global__ void k_zero(float4* __restrict__ g, float4* __restrict__ m) {
    int i = blockIdx.x * 256 + threadIdx.x;
    float4 z = make_float4(0.f, 0.f, 0.f, 0.f);
    if (i < GRID_F4)  g[i] = z;
    if (i < OMASK_F4) m[i] = z;
}

// ---- build: grid ids (+1, 0=empty) AND output-position occupancy mask ----
__global__ void k_build(const int* __restrict__ coors, unsigned short* __restrict__ grid,
                        unsigned char* __restrict__ omask) {
    int n = blockIdx.x * 256 + threadIdx.x;
    if (n >= NVOX) return;
    int b = coors[4*n+0], z = coors[4*n+1], y = coors[4*n+2], x = coors[4*n+3];
    int zp = z + 1, yp = y + 1, xp = x + 1;
    grid[((b*PD + zp)*PH + yp)*PW + xp] = (unsigned short)(n + 1);
    int dz[2], pz[2], dy[2], py[2], dx[2], px[2];
    int nz = axis_taps(zp, DO_, dz, pz);
    int ny = axis_taps(yp, HO_, dy, py);
    int nx = axis_taps(xp, WO_, dx, px);
    int bofs = b * OPP;
    for (int iz = 0; iz < nz; ++iz)
        for (int iy = 0; iy < ny; ++iy)
            for (int ix = 0; ix < nx; ++ix)
                omask[bofs + (pz[iz]*HO_ + py[iy])*WO_ + px[ix]] = 1;  // races benign
}

// ---- subm conv 1: 128 -> 16, ReLU. block = 16 voxels x 16 d; nbr in-block ----
__global__ void k_subm1(const float* __restrict__ feat, const float* __restrict__ W1,
                        const int* __restrict__ coors, const unsigned short* __restrict__ grid,
                        float* __restrict__ x1) {
    __shared__ int s_base[16];
    __shared__ int s_cnt[16];
    __shared__ int s_list[16][27];
    int base = blockIdx.x * 16;            // NVOX % 16 == 0: no bounds checks
    int t = threadIdx.x;
    if (t < 16) {
        int n = base + t;
        int b = coors[4*n+0], z = coors[4*n+1], y = coors[4*n+2], x = coors[4*n+3];
        s_base[t] = ((b*PD + z)*PH + y)*PW + x;   // tap k adds dz*PH*PW+dy*PW+dx
        s_cnt[t] = 0;
    }
    __syncthreads();
    for (int i = t; i < 16*27; i += 256) {
        int v = i / 27, k = i % 27;
        int dz = k / 9, dy = (k / 3) % 3, dx = k % 3;
        int id = (int)grid[s_base[v] + dz*(PH*PW) + dy*PW + dx] - 1;
        if (id >= 0) {
            int pos = atomicAdd(&s_cnt[v], 1);
            s_list[v][pos] = (k << 16) | id;
        }
    }
    __syncthreads();
    int v = t >> 4, d = t & 15;
    int cnt = s_cnt[v];
    float acc = 0.f;
    for (int tap = 0; tap < cnt; ++tap) {
        int pk = s_list[v][tap];
        int k = pk >> 16, idx = pk & 0xFFFF;
        const float4* f4 = (const float4*)(feat + (size_t)idx * C1);
        const float* w = W1 + k * (C1*16) + d;
        #pragma unroll 8
        for (int c4 = 0; c4 < 32; ++c4) {
            float4 f = f4[c4];
            acc += f.x * w[(c4*4+0)*16];
            acc += f.y * w[(c4*4+1)*16];
            acc += f.z * w[(c4*4+2)*16];
            acc += f.w * w[(c4*4+3)*16];
        }
    }
    x1[(base + v)*16 + d] = fmaxf(acc, 0.f);
}

// ---- subm conv 2: 16 -> 16, ReLU. same structure ----
__global__ void k_subm2(const float* __restrict__ x1, const float* __restrict__ W2,
                        const int* __restrict__ coors, const unsigned short* __restrict__ grid,
                        float* __restrict__ x2) {
    __shared__ int s_base[16];
    __shared__ int s_cnt[16];
    __shared__ int s_list[16][27];
    int base = blockIdx.x * 16;
    int t = threadIdx.x;
    if (t < 16) {
        int n = base + t;
        int b = coors[4*n+0], z = coors[4*n+1], y = coors[4*n+2], x = coors[4*n+3];
        s_base[t] = ((b*PD + z)*PH + y)*PW + x;
        s_cnt[t] = 0;
    }
    __syncthreads();
    for (int i = t; i < 16*27; i += 256) {
        int v = i / 27, k = i % 27;
        int dz = k / 9, dy = (k / 3) % 3, dx = k % 3;
        int id = (int)grid[s_base[v] + dz*(PH*PW) + dy*PW + dx] - 1;
        if (id >= 0) {
            int pos = atomicAdd(&s_cnt[v], 1);
            s_list[v][pos] = (k << 16) | id;
        }
    }
    __syncthreads();
    int v = t >> 4, d = t & 15;
    int cnt = s_cnt[v];
    float acc = 0.f;
    for (int tap = 0; tap < cnt; ++tap) {
        int pk = s_list[v][tap];
        int k = pk >> 16, idx = pk & 0xFFFF;
        const float4* xr = (const float4*)(x1 + (size_t)idx * 16);
        float4 a0 = xr[0], a1 = xr[1], a2 = xr[2], a3 = xr[3];
        const float* w = W2 + k * 256 + d;
        acc += a0.x*w[0*16]  + a0.y*w[1*16]  + a0.z*w[2*16]  + a0.w*w[3*16]
             + a1.x*w[4*16]  + a1.y*w[5*16]  + a1.z*w[6*16]  + a1.w*w[7*16]
             + a2.x*w[8*16]  + a2.y*w[9*16]  + a2.z*w[10*16] + a2.w*w[11*16]
             + a3.x*w[12*16] + a3.y*w[13*16] + a3.z*w[14*16] + a3.w*w[15*16];
    }
    x2[(base + v)*16 + d] = fmaxf(acc, 0.f);
}

// ---- dense output gather: 16 -> 32, fused ReLU; writes EVERY element once ----
// block = 256 threads = 32 positions x 8 float4-channel-quads
__global__ void k_out(const float* __restrict__ x2, const float* __restrict__ W3,
                      const unsigned short* __restrict__ grid,
                      const unsigned char* __restrict__ omask,
                      float4* __restrict__ out4) {
    __shared__ int s_base[32];
    __shared__ int s_cnt[32];
    __shared__ int s_list[32][27];
    __shared__ unsigned char s_occ[32];
    int pbase = blockIdx.x * 32;           // OUT_POS % 32 == 0
    int t = threadIdx.x;
    if (t < 32) {
        int p = pbase + t;
        s_occ[t] = omask[p];
        s_cnt[t] = 0;
        int b   = p / OPP,       rem = p - b * OPP;
        int pz  = rem / (HO_*WO_), r2 = rem - pz * (HO_*WO_);
        int py  = r2 / WO_,       px = r2 - py * WO_;
        // input padded coord = 2*pout + doff; max 2*(dim-1)+2 = pdim-1: in-bounds
        s_base[t] = ((b*PD + 2*pz)*PH + 2*py)*PW + 2*px;
    }
    __syncthreads();
    for (int i = t; i < 32*27; i += 256) {
        int v = i / 27;
        if (!s_occ[v]) continue;
        int k = i % 27;
        int dz = k / 9, dy = (k / 3) % 3, dx = k % 3;
        int id = (int)grid[s_base[v] + dz*(PH*PW) + dy*PW + dx] - 1;
        if (id >= 0) {
            int pos = atomicAdd(&s_cnt[v], 1);
            s_list[v][pos] = (k << 16) | id;
        }
    }
    __syncthreads();
    int v = t >> 3, c4 = t & 7;
    float4 acc = make_float4(0.f, 0.f, 0.f, 0.f);
    if (s_occ[v]) {
        int cnt = s_cnt[v];
        for (int tap = 0; tap < cnt; ++tap) {
            int pk = s_list[v][tap];
            int k = pk >> 16, idx = pk & 0xFFFF;
            const float*  xp = x2 + (size_t)idx * 16;
            const float4* w4 = (const float4*)(W3 + k*512 + c4*4);  // [c] stride 8 f4
            #pragma unroll
            for (int c = 0; c < 16; ++c) {
                float xv = xp[c];
                float4 w = w4[c * 8];
                acc.x += xv * w.x; acc.y += xv * w.y;
                acc.z += xv * w.z; acc.w += xv * w.w;
            }
        }
        acc.x = fmaxf(acc.x, 0.f); acc.y = fmaxf(acc.y, 0.f);
        acc.z = fmaxf(acc.z, 0.f); acc.w = fmaxf(acc.w, 0.f);
    }
    out4[(size_t)(pbase + v) * 8 + c4] = acc;   // fully coalesced float4 stores
}

extern "C" void kernel_launch(void* const* d_in, const int* in_sizes, int n_in,
                              void* d_out, int out_size, void* d_ws, size_t ws_size,
                              hipStream_t stream) {
    const float* feat  = (const float*)d_in[0];  // f32 (N,128)
    const int*   coors = (const int*)d_in[1];    // int32 (N,4)
    const float* W1    = (const float*)d_in[2];  // f32 (27,128,16)
    const float* W2    = (const float*)d_in[3];  // f32 (27,16,16)
    const float* W3    = (const float*)d_in[4];  // f32 (27,16,32)
    float* out = (float*)d_out;                  // f32 (2,21,200,176,32)

    char* ws = (char*)d_ws;
    size_t off = 0;
    unsigned short* grid = (unsigned short*)(ws + off);
    off += (((size_t)GRID_CELLS*2) + 255) & ~(size_t)255;
    unsigned char* omask = (unsigned char*)(ws + off);
    off += ((size_t)OUT_POS + 255) & ~(size_t)255;
    float* x1 = (float*)(ws + off); off += (((size_t)NVOX*16*4) + 255) & ~(size_t)255;
    float* x2 = (float*)(ws + off);

    k_zero <<<(GRID_F4 + 255) / 256, 256, 0, stream>>>((float4*)grid, (float4*)omask);
    k_build<<<(NVOX + 255) / 256, 256, 0, stream>>>(coors, grid, omask);
    k_subm1<<<NVOX / 16, 256, 0, stream>>>(feat, W1, coors, grid, x1);
    k_subm2<<<NVOX / 16, 256, 0, stream>>>(x1, W2, coors, grid, x2);
    k_out  <<<OUT_POS / 32, 256, 0, stream>>>(x2, W3, grid, omask, (float4*)out);
}